// Round 11
// baseline (145.528 us; speedup 1.0000x reference)
//
#include <hip/hip_runtime.h>
#include <hip/hip_bf16.h>

typedef __attribute__((ext_vector_type(8))) short bf16x8;
typedef __attribute__((ext_vector_type(4))) float f32x4;

#define CO    256
#define CI    2048
#define BATCH 8
#define HW    1024
#define NTOT  (BATCH * CI * HW)

#define BM    128         // co per block (2 co-tiles)
#define BHW   32          // hw per block
#define BK    128         // k per step (16 steps total)
#define LDA   136         // padded row stride in shorts (272B -> row bank base rotates by 4)

static __device__ __forceinline__ float fabs4max(const float4 v) {
  return fmaxf(fmaxf(fabsf(v.x), fabsf(v.y)), fmaxf(fabsf(v.z), fabsf(v.w)));
}

static __device__ __forceinline__ short f32_to_bf16_bits(float f) {
  return (short)(__float_as_uint(f) >> 16);
}

static __device__ __forceinline__ short quant1(float v, float inv_s) {
  return f32_to_bf16_bits(fminf(fmaxf(rintf(v * inv_s), -128.0f), 127.0f));
}

// ---- K1: global abs-max of x (4-way ILP) ----------------------------------
__global__ __launch_bounds__(256) void absmax_kernel(const float* __restrict__ x,
                                                     unsigned int* __restrict__ absbits,
                                                     long long n4) {
  long long i = (long long)blockIdx.x * blockDim.x + threadIdx.x;
  const long long stride = (long long)gridDim.x * blockDim.x;
  const float4* x4 = (const float4*)x;
  float m0 = 0.0f, m1 = 0.0f, m2 = 0.0f, m3 = 0.0f;
  for (; i + 3 * stride < n4; i += 4 * stride) {
    m0 = fmaxf(m0, fabs4max(x4[i]));
    m1 = fmaxf(m1, fabs4max(x4[i + stride]));
    m2 = fmaxf(m2, fabs4max(x4[i + 2 * stride]));
    m3 = fmaxf(m3, fabs4max(x4[i + 3 * stride]));
  }
  for (; i < n4; i += stride) m0 = fmaxf(m0, fabs4max(x4[i]));
  float m = fmaxf(fmaxf(m0, m1), fmaxf(m2, m3));
#pragma unroll
  for (int off = 32; off; off >>= 1) m = fmaxf(m, __shfl_xor(m, off));
  __shared__ float red[4];
  if ((threadIdx.x & 63) == 0) red[threadIdx.x >> 6] = m;
  __syncthreads();
  if (threadIdx.x == 0) {
    m = fmaxf(fmaxf(red[0], red[1]), fmaxf(red[2], red[3]));
    atomicMax(absbits, __float_as_uint(m));   // vals >= 0: bit order = uint order
  }
}

// ---- K2: per-output-channel weight quant + alpha/beta ---------------------
__global__ __launch_bounds__(256) void wquant_kernel(const float* __restrict__ w,
                                                     const float* __restrict__ bias,
                                                     const unsigned int* __restrict__ absbits,
                                                     short* __restrict__ qw,
                                                     float* __restrict__ alpha,
                                                     float* __restrict__ beta) {
  const int co = blockIdx.x;
  const int t = threadIdx.x;
  const float* row = w + (size_t)co * CI;
  const float4 v0 = ((const float4*)row)[t * 2];
  const float4 v1 = ((const float4*)row)[t * 2 + 1];
  float m = fmaxf(fabs4max(v0), fabs4max(v1));
#pragma unroll
  for (int off = 32; off; off >>= 1) m = fmaxf(m, __shfl_xor(m, off));
  __shared__ float red[4];
  __shared__ float s_sw;
  if ((t & 63) == 0) red[t >> 6] = m;
  __syncthreads();
  if (t == 0) {
    const float mm = fmaxf(fmaxf(red[0], red[1]), fmaxf(red[2], red[3]));
    s_sw = fmaxf(mm, 1e-8f) / 127.0f;
  }
  __syncthreads();
  const float sw = s_sw;

  const float vals[8] = {v0.x, v0.y, v0.z, v0.w, v1.x, v1.y, v1.z, v1.w};
  bf16x8 qv;
#pragma unroll
  for (int j = 0; j < 8; ++j) {
    const float q = fminf(fmaxf(rintf(vals[j] / sw), -128.0f), 127.0f);
    qv[j] = f32_to_bf16_bits(q);
  }
  *(bf16x8*)(qw + (size_t)co * CI + t * 8) = qv;

  if (t == 0) {
    const float sa = fmaxf(__uint_as_float(*absbits), 1e-8f) / 127.0f;
    const float a = sa * sw;
    alpha[co] = a;
    beta[co] = rintf(bias[co] / a) * a;
  }
}

// ---- K3: swapped-operand bf16 MFMA GEMM, BK=128 ---------------------------
// D[r=hw][c=co]; block = 128co x 32hw; 512 thr = 8 waves (4 wco x 2 whw).
// 16 K-steps; per step: A-stage 32KB (coalesced, 16 lanes/row), B 16KB x-quant.
// LDS rows 272B => bank base rotates 4/row: frag reads & stage writes 2-way (free).
// 43.5 KB LDS -> 3 blocks/CU for cross-block latency overlap.
__global__ __launch_bounds__(512) void gemm_kernel(const float* __restrict__ x,
                                                   const short* __restrict__ qw,
                                                   const float* __restrict__ alpha,
                                                   const float* __restrict__ beta,
                                                   const unsigned int* __restrict__ absbits,
                                                   float* __restrict__ out) {
  __shared__ short As[BM * LDA];    // 34.8 KB
  __shared__ short Bs[BHW * LDA];   // 8.7 KB

  const int bx = blockIdx.x;
  const int T = (bx & 7) | ((bx >> 4) << 3);  // tile id (XCD pairing for co-twins)
  const int cot = (bx >> 3) & 1;
  const int hwt = T & 31;
  const int b = T >> 5;
  const int co0 = cot * BM;
  const int hw0 = hwt * BHW;

  const float sa = fmaxf(__uint_as_float(*absbits), 1e-8f) / 127.0f;
  const float inv_sa = 1.0f / sa;

  const int t = threadIdx.x;
  const int lane = t & 63;
  const int w = t >> 6;              // 0..7
  const int wco = (w & 3) * 32;      // co group (32 wide)
  const int whw = (w >> 2) * 16;     // hw group (16 wide)
  const int lr = lane & 15;
  const int kg = lane >> 4;          // 0..3

  // A staging: unit u = s*512+t -> row=u>>4 (0..127), slot=u&15 (16B each).
  // 16 consecutive lanes cover one full 256B row chunk: fully coalesced.
  int arow[4], aslot[4];
  const short* apA[4];
#pragma unroll
  for (int s = 0; s < 4; ++s) {
    const int u = s * 512 + t;
    arow[s] = u >> 4;
    aslot[s] = u & 15;
    apA[s] = qw + (size_t)(co0 + arow[s]) * CI + aslot[s] * 8;
  }
  // B staging: unit u = s*512+t -> k=u>>3 (0..127), chunk=u&7 (4 hw each).
  int bks[2], bch[2];
  const float* xpB[2];
#pragma unroll
  for (int s = 0; s < 2; ++s) {
    const int u = s * 512 + t;
    bks[s] = u >> 3;
    bch[s] = (u & 7) * 4;
    xpB[s] = x + ((size_t)b * CI + bks[s]) * HW + hw0 + bch[s];
  }

  f32x4 acc[2] = {};

  bf16x8 avA[4];
  float4 xv[2];
#pragma unroll
  for (int s = 0; s < 4; ++s) avA[s] = *(const bf16x8*)(apA[s]);
#pragma unroll
  for (int s = 0; s < 2; ++s) xv[s] = *(const float4*)(xpB[s]);

  for (int k0 = 0; k0 < CI; k0 += BK) {
    __syncthreads();   // prior compute done before overwriting LDS
#pragma unroll
    for (int s = 0; s < 4; ++s)
      *(bf16x8*)&As[arow[s] * LDA + aslot[s] * 8] = avA[s];
#pragma unroll
    for (int s = 0; s < 2; ++s) {
      const float f[4] = {xv[s].x, xv[s].y, xv[s].z, xv[s].w};
#pragma unroll
      for (int j = 0; j < 4; ++j)
        Bs[(bch[s] + j) * LDA + bks[s]] = quant1(f[j], inv_sa);
    }

    // prefetch next K-tile (wrapped on last iter; values discarded)
    const int kn = (k0 + BK) & (CI - 1);
#pragma unroll
    for (int s = 0; s < 4; ++s) avA[s] = *(const bf16x8*)(apA[s] + kn);
#pragma unroll
    for (int s = 0; s < 2; ++s) xv[s] = *(const float4*)(xpB[s] + (size_t)kn * HW);

    __syncthreads();

#pragma unroll
    for (int h = 0; h < 4; ++h) {
      const int off = (h * 4 + kg) * 8;
      const bf16x8 aF = *(const bf16x8*)&Bs[(whw + lr) * LDA + off];
#pragma unroll
      for (int n = 0; n < 2; ++n) {
        const bf16x8 bF = *(const bf16x8*)&As[(wco + n * 16 + lr) * LDA + off];
        acc[n] = __builtin_amdgcn_mfma_f32_16x16x32_bf16(aF, bF, acc[n], 0, 0, 0);
      }
    }
  }

  // epilogue: D row = hw = kg*4 + reg (4 consecutive hw per lane), D col = co
  const int hwo = hw0 + whw + kg * 4;
#pragma unroll
  for (int n = 0; n < 2; ++n) {
    const int co = co0 + wco + n * 16 + lr;
    const float af = alpha[co];
    const float bf = beta[co];
    float4 v;
    v.x = acc[n][0] * af + bf;
    v.y = acc[n][1] * af + bf;
    v.z = acc[n][2] * af + bf;
    v.w = acc[n][3] * af + bf;
    *(float4*)(out + ((size_t)(b * CO + co)) * HW + hwo) = v;
  }
}

extern "C" void kernel_launch(void* const* d_in, const int* in_sizes, int n_in,
                              void* d_out, int out_size, void* d_ws, size_t ws_size,
                              hipStream_t stream) {
  const float* x    = (const float*)d_in[0];
  const float* wgt  = (const float*)d_in[1];
  const float* bias = (const float*)d_in[2];
  float* out = (float*)d_out;

  unsigned int* absbits = (unsigned int*)d_ws;
  short* qw    = (short*)((char*)d_ws + 256);
  float* alpha = (float*)((char*)d_ws + 256 + (size_t)CO * CI * 2);
  float* beta  = alpha + CO;

  hipMemsetAsync(d_ws, 0, 4, stream);
  absmax_kernel<<<2048, 256, 0, stream>>>(x, absbits, (long long)(NTOT / 4));
  wquant_kernel<<<CO, 256, 0, stream>>>(wgt, bias, absbits, qw, alpha, beta);
  gemm_kernel<<<2 * 32 * BATCH, 512, 0, stream>>>(x, qw, alpha, beta, absbits, out);
}